// Round 5
// baseline (539.671 us; speedup 1.0000x reference)
//
#include <hip/hip_runtime.h>
#include <hip/hip_bf16.h>
#include <cstdint>
#include <cstddef>

#define DM     1024
#define DSTATE 16
#define SEQ    4096
#define BATCH  8
#define MROWS  (BATCH * SEQ)   // 32768
#define LNEPS  1e-5f

#define CHUNK  64
#define WARM   16
#define NCHUNK (SEQ / CHUNK)   // 64

typedef __hip_bfloat16 bf16;
typedef __attribute__((ext_vector_type(8))) short short8;
typedef __attribute__((ext_vector_type(4))) float f32x4;

static __device__ __forceinline__ unsigned short f2bf(float f) {
  bf16 h = __float2bfloat16(f);
  return __builtin_bit_cast(unsigned short, h);
}

#define GLDS16(SRC, DSTOFF, LDSBASE)                                          \
  __builtin_amdgcn_global_load_lds(                                           \
      (const __attribute__((address_space(1))) void*)(SRC),                   \
      (__attribute__((address_space(3))) void*)((LDSBASE) + (DSTOFF)), 16, 0, 0)

// ---------------------------------------------------------------------------
// K1a: x (f32) -> bf16 wsx, 8 elems/thread. (proven)
// ---------------------------------------------------------------------------
__global__ __launch_bounds__(256) void canon_x(const float* __restrict__ xin,
                                               bf16* __restrict__ wsx) {
  size_t i = ((size_t)blockIdx.x * 256 + threadIdx.x) * 8;
  const float4* p = (const float4*)(xin + i);
  float4 a = p[0], b = p[1];
  uint4 o;
  o.x = (unsigned)f2bf(a.x) | ((unsigned)f2bf(a.y) << 16);
  o.y = (unsigned)f2bf(a.z) | ((unsigned)f2bf(a.w) << 16);
  o.z = (unsigned)f2bf(b.x) | ((unsigned)f2bf(b.y) << 16);
  o.w = (unsigned)f2bf(b.z) | ((unsigned)f2bf(b.w) << 16);
  *(uint4*)(wsx + i) = o;
}

// ---------------------------------------------------------------------------
// K1b: gate_w (f32) -> bf16.
// ---------------------------------------------------------------------------
__global__ __launch_bounds__(256) void canon_gw(const float* __restrict__ gw,
                                                bf16* __restrict__ gwc) {
  size_t i = ((size_t)blockIdx.x * 256 + threadIdx.x) * 8;
  const float4* p = (const float4*)(gw + i);
  float4 a = p[0], b = p[1];
  uint4 o;
  o.x = (unsigned)f2bf(a.x) | ((unsigned)f2bf(a.y) << 16);
  o.y = (unsigned)f2bf(a.z) | ((unsigned)f2bf(a.w) << 16);
  o.z = (unsigned)f2bf(b.x) | ((unsigned)f2bf(b.y) << 16);
  o.w = (unsigned)f2bf(b.z) | ((unsigned)f2bf(b.w) << 16);
  *(uint4*)(gwc + i) = o;
}

// ---------------------------------------------------------------------------
// K2: Bx via MFMA (proven in round 4).
// ---------------------------------------------------------------------------
__global__ __launch_bounds__(256) void bx_kernel(const bf16* __restrict__ X,
                                                 const float* __restrict__ Bw,
                                                 const float* __restrict__ Bb,
                                                 float* __restrict__ Bx) {
  __shared__ __align__(16) char lds[40960];   // BwT 32KB + A dbuf 2x4KB
  const int tid  = threadIdx.x;
  const int lane = tid & 63;
  const int w    = tid >> 6;                  // 0..3
  const int fm   = lane & 15;
  const int fq   = lane >> 4;
  const int l4   = lane >> 2, lk = lane & 3;
  const int m0   = blockIdx.x * 64;

  // ---- convert Bw -> bf16 LDS: byte = step*1024 + n*64 + ((cq^((n>>1)&3))<<4)
  {
    int t6   = tid & 63;
    int nb   = tid >> 6;
    int step = t6 >> 1;
    int cq0  = (t6 & 1) * 2;
#pragma unroll
    for (int p = 0; p < 4; ++p) {
      int n = p * 4 + nb;
      const float4* src = (const float4*)(Bw + (size_t)n * DM + t6 * 16);
      float4 a = src[0], b = src[1], c = src[2], d = src[3];
      uint4 o0, o1;
      o0.x = (unsigned)f2bf(a.x) | ((unsigned)f2bf(a.y) << 16);
      o0.y = (unsigned)f2bf(a.z) | ((unsigned)f2bf(a.w) << 16);
      o0.z = (unsigned)f2bf(b.x) | ((unsigned)f2bf(b.y) << 16);
      o0.w = (unsigned)f2bf(b.z) | ((unsigned)f2bf(b.w) << 16);
      o1.x = (unsigned)f2bf(c.x) | ((unsigned)f2bf(c.y) << 16);
      o1.y = (unsigned)f2bf(c.z) | ((unsigned)f2bf(c.w) << 16);
      o1.z = (unsigned)f2bf(d.x) | ((unsigned)f2bf(d.y) << 16);
      o1.w = (unsigned)f2bf(d.z) | ((unsigned)f2bf(d.w) << 16);
      int sw = (n >> 1) & 3;
      *(uint4*)(lds + step * 1024 + n * 64 + ((cq0 ^ sw) << 4))       = o0;
      *(uint4*)(lds + step * 1024 + n * 64 + (((cq0 + 1) ^ sw) << 4)) = o1;
    }
  }

  const int rowA = w * 16 + l4;
  const int kqA  = lk ^ ((rowA >> 1) & 3);
  GLDS16(X + (size_t)(m0 + rowA) * DM + kqA * 8, 32768 + w * 1024, lds);
  __syncthreads();

  const int rA   = w * 16 + fm;
  const int offA = rA * 64 + ((fq ^ ((rA >> 1) & 3)) << 4);
  const int offB = fm * 64 + ((fq ^ ((fm >> 1) & 3)) << 4);

  f32x4 acc = (f32x4)(0.f);
  for (int t = 0; t < 32; ++t) {
    const int cb = 32768 + (t & 1) * 4096;
    const int sb = 32768 + 4096 - (t & 1) * 4096;
    if (t < 31)
      GLDS16(X + (size_t)(m0 + rowA) * DM + (t + 1) * 32 + kqA * 8,
             sb + w * 1024, lds);
    short8 af  = *(const short8*)(lds + cb + offA);
    short8 bfv = *(const short8*)(lds + t * 1024 + offB);
    acc = __builtin_amdgcn_mfma_f32_16x16x32_bf16(af, bfv, acc, 0, 0, 0);
    __syncthreads();
  }
  float bb = Bb[fm];
#pragma unroll
  for (int q = 0; q < 4; ++q) {
    int row = m0 + w * 16 + fq * 4 + q;
    Bx[(size_t)row * DSTATE + fm] = acc[q] + bb;
  }
}

// ---------------------------------------------------------------------------
// K3: chunked scan. state_t = tanh(A @ state_{t-1} + bx_t).
// tanhf (library call) replaced with overflow-safe __expf form:
// t = exp(-2|a|); r = (1-t)/(1+t); state = copysign(r, a).  err ~1e-6.
// ---------------------------------------------------------------------------
__global__ __launch_bounds__(64) void scan_kernel(const float* __restrict__ A,
                                                  const float* __restrict__ Bx,
                                                  float* __restrict__ st) {
  int lane = threadIdx.x;
  int n    = lane & 15;
  int base = lane & 48;
  int chain = blockIdx.x * 4 + (lane >> 4);
  int c = chain >> 3;
  int b = chain & 7;

  float Arow[16];
#pragma unroll
  for (int m = 0; m < 16; m++) Arow[m] = A[n * 16 + m];

  int t0   = (c == 0) ? 0 : c * CHUNK - WARM;
  int t1   = c * CHUNK;
  int tEnd = c * CHUNK + CHUNK;

  const float* bxp = Bx + (size_t)b * SEQ * DSTATE + n;
  float*       stp = st + (size_t)b * SEQ * DSTATE + n;

  float state = 0.f;
  for (int t = t0; t < tEnd; t++) {
    float a = bxp[(size_t)t * DSTATE];
#pragma unroll
    for (int m = 0; m < 16; m++)
      a += Arow[m] * __shfl(state, base + m, 64);
    float e = __expf(-2.f * fabsf(a));
    float r = (1.f - e) / (1.f + e);
    state = __builtin_copysignf(r, a);
    if (t >= t1) stp[(size_t)t * DSTATE] = state;
  }
}

// ---------------------------------------------------------------------------
// K4: FUSED gate GEMM + SSM output + gating + residual + LN.
// FBM=64: halves L2->LDS Gw staging (2.18 GB -> 1.09 GB; round-4 measured
// dur == staged_bytes / ~8 TB/s, so staging BW is the wall).
// Main loop = round-1 proven structure; epilogue = round-4 proven
// full-line bounce store (WRITE_SIZE clean at 133 MB).
// ---------------------------------------------------------------------------
#define FBM 64
#define FBK 32
#define NT  (DM / FBK)          // 32
#define BUFB 69632              // A [0,4096) + B [4096,69632)
#define CW_OFF 0                // epilogue Cw (64KB, overlays buf0)
#define ST_OFF 65536            // epilogue st (4KB, tail of buf0)
#define PART_OFF 69632          // LN partials: 8 waves x 64 rows x 8B = 4KB
#define TOT_OFF 73728           // LN (mu,inv) per row: 64 x 8B
#define BOUNCE 74240            // 16 rows x 4KB = 64KB store-bounce
// total LDS = 74240 + 65536 = 139776 <= 160K -> 1 block/CU

__global__ __launch_bounds__(512, 2) void fused_kernel(
    const bf16* __restrict__ X, const bf16* __restrict__ Gw,
    const float* __restrict__ xf, const float* __restrict__ st,
    const float* __restrict__ Cw, const float* __restrict__ Cb,
    const float* __restrict__ Dv, const float* __restrict__ gb,
    const float* __restrict__ lng, const float* __restrict__ lnb,
    float* __restrict__ out) {
  __shared__ __align__(16) char lds[139776];
  const int tid  = threadIdx.x;
  const int lane = tid & 63;
  const int w    = tid >> 6;        // wave 0..7
  const int fm   = lane & 15;
  const int fq   = lane >> 4;
  const int m0   = blockIdx.x * FBM;
  const int l4   = lane >> 2, lk = lane & 3;

  // staging source constants (pre-swizzled global addresses)
  int colS[8], kqS[8];
#pragma unroll
  for (int s = 0; s < 8; s++) {
    int col = (w * 8 + s) * 16 + l4;
    colS[s] = col;
    kqS[s]  = lk ^ ((col >> 1) & 3);
  }
  const int rowA = w * 16 + l4;     // valid for w<4
  const int kqA  = lk ^ ((rowA >> 1) & 3);

  // fragment read byte offsets (swizzled)
  int offA[4], offB[8];
#pragma unroll
  for (int i = 0; i < 4; i++) {
    int r = i * 16 + fm;
    offA[i] = r * 64 + ((fq ^ ((r >> 1) & 3)) << 4);
  }
#pragma unroll
  for (int j = 0; j < 8; j++) {
    int c = w * 128 + j * 16 + fm;
    offB[j] = 4096 + c * 64 + ((fq ^ ((c >> 1) & 3)) << 4);
  }

  f32x4 acc[4][8];
#pragma unroll
  for (int i = 0; i < 4; i++)
#pragma unroll
    for (int j = 0; j < 8; j++) acc[i][j] = (f32x4)(0.f);

  // prologue: tile 0 -> buf0
  {
#pragma unroll
    for (int s = 0; s < 8; s++)
      GLDS16(Gw + (size_t)colS[s] * DM + kqS[s] * 8,
             4096 + (w * 8 + s) * 1024, lds);
    if (w < 4)
      GLDS16(X + (size_t)(m0 + rowA) * DM + kqA * 8, w * 1024, lds);
  }
  __syncthreads();

  for (int t = 0; t < NT; t++) {
    const int cb = (t & 1) * BUFB;  // compute buffer base
    const int sb = BUFB - cb;       // stage buffer base
    if (t < NT - 1) {
      const int kb = (t + 1) * FBK;
#pragma unroll
      for (int s = 0; s < 8; s++)
        GLDS16(Gw + (size_t)colS[s] * DM + kb + kqS[s] * 8,
               sb + 4096 + (w * 8 + s) * 1024, lds);
      if (w < 4)
        GLDS16(X + (size_t)(m0 + rowA) * DM + kb + kqA * 8, sb + w * 1024, lds);
    } else {
      // last K-step (t=31 computes from buf1): stage epilogue into buf0
#pragma unroll
      for (int s = 0; s < 8; s++) {
        int c   = w * 8 + s;
        int col = c * 16 + l4;
        int nq  = lk ^ ((col >> 1) & 3);
        GLDS16(Cw + (size_t)col * DSTATE + nq * 4, CW_OFF + c * 1024, lds);
      }
      if (w >= 4) {
        int cc  = w - 4;
        int row = cc * 16 + l4;
        int nq  = lk ^ ((row >> 1) & 3);
        GLDS16(st + (size_t)(m0 + row) * DSTATE + nq * 4, ST_OFF + cc * 1024, lds);
      }
    }

    short8 af[4];
#pragma unroll
    for (int i = 0; i < 4; i++) af[i] = *(const short8*)(lds + cb + offA[i]);
#pragma unroll
    for (int j = 0; j < 8; j++) {
      short8 bfj = *(const short8*)(lds + cb + offB[j]);
#pragma unroll
      for (int i = 0; i < 4; i++)
        acc[i][j] = __builtin_amdgcn_mfma_f32_16x16x32_bf16(af[i], bfj,
                                                            acc[i][j], 0, 0, 0);
    }
    __syncthreads();
  }

  // ---- epilogue phase 1: z2 = g*oc + (1-g)*x + x, row partial sums
#pragma unroll
  for (int i = 0; i < 4; i++) {
    float ocp[8][4];
#pragma unroll
    for (int j = 0; j < 8; j++)
#pragma unroll
      for (int r = 0; r < 4; r++) ocp[j][r] = 0.f;

#pragma unroll
    for (int nq = 0; nq < 4; nq++) {
      f32x4 stv[4];
#pragma unroll
      for (int r = 0; r < 4; r++) {
        int row = i * 16 + fq * 4 + r;
        stv[r] = *(const f32x4*)(lds + ST_OFF + row * 64 +
                                 ((nq ^ ((row >> 1) & 3)) << 4));
      }
#pragma unroll
      for (int j = 0; j < 8; j++) {
        int c = w * 128 + j * 16 + fm;
        f32x4 cw = *(const f32x4*)(lds + CW_OFF + c * 64 +
                                   ((nq ^ ((c >> 1) & 3)) << 4));
#pragma unroll
        for (int r = 0; r < 4; r++)
          ocp[j][r] += stv[r][0] * cw[0] + stv[r][1] * cw[1] +
                       stv[r][2] * cw[2] + stv[r][3] * cw[3];
      }
    }

    float sum4[4] = {0.f, 0.f, 0.f, 0.f};
    float ssq4[4] = {0.f, 0.f, 0.f, 0.f};
#pragma unroll
    for (int j = 0; j < 8; j++) {
      int c = w * 128 + j * 16 + fm;
      float gbv = gb[c], cbv = Cb[c], dvv = Dv[c];
#pragma unroll
      for (int r = 0; r < 4; r++) {
        int   grow = m0 + i * 16 + fq * 4 + r;
        float xv = xf[(size_t)grow * DM + c];
        float zg = acc[i][j][r] + gbv;
        float g  = zg / (1.f + __expf(-zg));
        float ocf = ocp[j][r] + cbv + dvv * xv;
        float y  = g * ocf + (1.f - g) * xv;
        float z2 = y + xv;
        acc[i][j][r] = z2;
        sum4[r] += z2;
        ssq4[r] += z2 * z2;
      }
    }
#pragma unroll
    for (int r = 0; r < 4; r++) {
#pragma unroll
      for (int off = 1; off < 16; off <<= 1) {
        sum4[r] += __shfl_xor(sum4[r], off, 64);
        ssq4[r] += __shfl_xor(ssq4[r], off, 64);
      }
    }
    if (fm == 0) {
#pragma unroll
      for (int r = 0; r < 4; r++) {
        int row = i * 16 + fq * 4 + r;
        *(float2*)(lds + PART_OFF + w * 512 + row * 8) =
            make_float2(sum4[r], ssq4[r]);
      }
    }
  }
  __syncthreads();

  if (tid < 64) {
    float s = 0.f, q = 0.f;
#pragma unroll
    for (int ww = 0; ww < 8; ww++) {
      float2 p = *(const float2*)(lds + PART_OFF + ww * 512 + tid * 8);
      s += p.x; q += p.y;
    }
    float mu  = s * (1.f / DM);
    float var = q * (1.f / DM) - mu * mu;
    *(float2*)(lds + TOT_OFF + tid * 8) = make_float2(mu, rsqrtf(var + LNEPS));
  }
  __syncthreads();

  // ---- epilogue phase 2: bounce raw z2 through LDS, store float4 full lines
  for (int h = 0; h < 4; ++h) {
#pragma unroll
    for (int j = 0; j < 8; ++j) {
      int c = w * 128 + j * 16 + fm;
#pragma unroll
      for (int r = 0; r < 4; ++r) {
        int row16 = fq * 4 + r;
        *(float*)(lds + BOUNCE + row16 * 4096 + c * 4) = acc[h][j][r];
      }
    }
    __syncthreads();
    {
      int row16 = tid >> 5;
      int lbase = (tid & 31) * 4;
      float2 mi = *(const float2*)(lds + TOT_OFF + (h * 16 + row16) * 8);
#pragma unroll
      for (int q = 0; q < 8; ++q) {
        int col = lbase + q * 128;
        f32x4 z = *(const f32x4*)(lds + BOUNCE + row16 * 4096 + col * 4);
        float4 g4 = *(const float4*)(lng + col);
        float4 b4 = *(const float4*)(lnb + col);
        float4 ov;
        ov.x = (z[0] - mi.x) * mi.y * g4.x + b4.x;
        ov.y = (z[1] - mi.x) * mi.y * g4.y + b4.y;
        ov.z = (z[2] - mi.x) * mi.y * g4.z + b4.z;
        ov.w = (z[3] - mi.x) * mi.y * g4.w + b4.w;
        *(float4*)(out + (size_t)(m0 + h * 16 + row16) * DM + col) = ov;
      }
    }
    __syncthreads();
  }
}

// ---------------------------------------------------------------------------
extern "C" void kernel_launch(void* const* d_in, const int* in_sizes, int n_in,
                              void* d_out, int out_size, void* d_ws, size_t ws_size,
                              hipStream_t stream) {
  (void)in_sizes; (void)n_in;
  const float* x   = (const float*)d_in[0];
  const float* A   = (const float*)d_in[1];
  const float* Bw  = (const float*)d_in[2];
  const float* Bb  = (const float*)d_in[3];
  const float* Cw  = (const float*)d_in[4];
  const float* Cb  = (const float*)d_in[5];
  const float* Dv  = (const float*)d_in[6];
  const float* Gw  = (const float*)d_in[7];
  const float* gb  = (const float*)d_in[8];
  const float* lng = (const float*)d_in[9];
  const float* lnb = (const float*)d_in[10];
  float* out = (float*)d_out;

  const size_t NEED = (size_t)72 << 20;
  if (ws_size < NEED) {
    hipMemsetAsync(d_out, 0, (size_t)out_size * 4, stream);
    return;
  }

  char* ws = (char*)d_ws;
  bf16*  wsx = (bf16*)(ws);                          // 64 MB bf16 x
  bf16*  gwc = (bf16*)(ws + ((size_t)64 << 20));     // 2 MB bf16 gate_w
  float* Bx  = (float*)(ws + ((size_t)66 << 20));    // 2 MB
  float* st  = (float*)(ws + ((size_t)68 << 20));    // 2 MB

  canon_x <<<MROWS * DM / (256 * 8), 256, 0, stream>>>(x, wsx);
  canon_gw<<<DM * DM / (256 * 8), 256, 0, stream>>>(Gw, gwc);
  bx_kernel<<<MROWS / 64, 256, 0, stream>>>(wsx, Bw, Bb, Bx);
  scan_kernel<<<(BATCH * NCHUNK) / 4, 64, 0, stream>>>(A, Bx, st);
  fused_kernel<<<MROWS / FBM, 512, 0, stream>>>(
      wsx, gwc, x, st, Cw, Cb, Dv, gb, lng, lnb, out);
}

// Round 6
// 500.027 us; speedup vs baseline: 1.0793x; 1.0793x over previous
//
#include <hip/hip_runtime.h>
#include <hip/hip_bf16.h>
#include <cstdint>
#include <cstddef>

#define DM     1024
#define DSTATE 16
#define SEQ    4096
#define BATCH  8
#define MROWS  (BATCH * SEQ)   // 32768
#define LNEPS  1e-5f

#define CHUNK  64
#define WARM   16
#define NCHUNK (SEQ / CHUNK)   // 64

typedef __hip_bfloat16 bf16;
typedef __attribute__((ext_vector_type(8))) short short8;
typedef __attribute__((ext_vector_type(4))) float f32x4;

static __device__ __forceinline__ unsigned short f2bf(float f) {
  bf16 h = __float2bfloat16(f);
  return __builtin_bit_cast(unsigned short, h);
}

#define GLDS16(SRC, DSTOFF, LDSBASE)                                          \
  __builtin_amdgcn_global_load_lds(                                           \
      (const __attribute__((address_space(1))) void*)(SRC),                   \
      (__attribute__((address_space(3))) void*)((LDSBASE) + (DSTOFF)), 16, 0, 0)

#define WAITV(N) asm volatile("s_waitcnt vmcnt(" #N ")" ::: "memory")

// ---------------------------------------------------------------------------
// K1: canon x AND gate_w -> bf16 in one launch (block-index split).
// ---------------------------------------------------------------------------
#define XBLK (MROWS * DM / (256 * 8))   // 16384
#define GBLK (DM * DM / (256 * 8))      // 512

__global__ __launch_bounds__(256) void canon_all(const float* __restrict__ xin,
                                                 const float* __restrict__ gw,
                                                 bf16* __restrict__ wsx,
                                                 bf16* __restrict__ gwc) {
  int blk = blockIdx.x;
  const float* src;
  bf16* dst;
  size_t i;
  if (blk < XBLK) {
    i = ((size_t)blk * 256 + threadIdx.x) * 8;
    src = xin; dst = wsx;
  } else {
    i = ((size_t)(blk - XBLK) * 256 + threadIdx.x) * 8;
    src = gw; dst = gwc;
  }
  const float4* p = (const float4*)(src + i);
  float4 a = p[0], b = p[1];
  uint4 o;
  o.x = (unsigned)f2bf(a.x) | ((unsigned)f2bf(a.y) << 16);
  o.y = (unsigned)f2bf(a.z) | ((unsigned)f2bf(a.w) << 16);
  o.z = (unsigned)f2bf(b.x) | ((unsigned)f2bf(b.y) << 16);
  o.w = (unsigned)f2bf(b.z) | ((unsigned)f2bf(b.w) << 16);
  *(uint4*)(dst + i) = o;
}

// ---------------------------------------------------------------------------
// K2: Bx via MFMA (round-4 proven) + counted-vmcnt pipeline (T4).
// Per step each of the 4 waves issues exactly 1 A-granule -> vmcnt(1).
// ---------------------------------------------------------------------------
__global__ __launch_bounds__(256) void bx_kernel(const bf16* __restrict__ X,
                                                 const float* __restrict__ Bw,
                                                 const float* __restrict__ Bb,
                                                 float* __restrict__ Bx) {
  __shared__ __align__(16) char lds[40960];   // BwT 32KB + A dbuf 2x4KB
  const int tid  = threadIdx.x;
  const int lane = tid & 63;
  const int w    = tid >> 6;                  // 0..3
  const int fm   = lane & 15;
  const int fq   = lane >> 4;
  const int l4   = lane >> 2, lk = lane & 3;
  const int m0   = blockIdx.x * 64;

  // ---- convert Bw -> bf16 LDS: byte = step*1024 + n*64 + ((cq^((n>>1)&3))<<4)
  {
    int t6   = tid & 63;
    int nb   = tid >> 6;
    int step = t6 >> 1;
    int cq0  = (t6 & 1) * 2;
#pragma unroll
    for (int p = 0; p < 4; ++p) {
      int n = p * 4 + nb;
      const float4* src = (const float4*)(Bw + (size_t)n * DM + t6 * 16);
      float4 a = src[0], b = src[1], c = src[2], d = src[3];
      uint4 o0, o1;
      o0.x = (unsigned)f2bf(a.x) | ((unsigned)f2bf(a.y) << 16);
      o0.y = (unsigned)f2bf(a.z) | ((unsigned)f2bf(a.w) << 16);
      o0.z = (unsigned)f2bf(b.x) | ((unsigned)f2bf(b.y) << 16);
      o0.w = (unsigned)f2bf(b.z) | ((unsigned)f2bf(b.w) << 16);
      o1.x = (unsigned)f2bf(c.x) | ((unsigned)f2bf(c.y) << 16);
      o1.y = (unsigned)f2bf(c.z) | ((unsigned)f2bf(c.w) << 16);
      o1.z = (unsigned)f2bf(d.x) | ((unsigned)f2bf(d.y) << 16);
      o1.w = (unsigned)f2bf(d.z) | ((unsigned)f2bf(d.w) << 16);
      int sw = (n >> 1) & 3;
      *(uint4*)(lds + step * 1024 + n * 64 + ((cq0 ^ sw) << 4))       = o0;
      *(uint4*)(lds + step * 1024 + n * 64 + (((cq0 + 1) ^ sw) << 4)) = o1;
    }
  }

  const int rowA = w * 16 + l4;
  const int kqA  = lk ^ ((rowA >> 1) & 3);
  GLDS16(X + (size_t)(m0 + rowA) * DM + kqA * 8, 32768 + w * 1024, lds);
  __syncthreads();   // BwT ds_writes visible; drains tile-0 (once, cheap)

  const int rA   = w * 16 + fm;
  const int offA = rA * 64 + ((fq ^ ((rA >> 1) & 3)) << 4);
  const int offB = fm * 64 + ((fq ^ ((fm >> 1) & 3)) << 4);

  f32x4 acc = (f32x4)(0.f);
  for (int t = 0; t < 32; ++t) {
    const int cb = 32768 + (t & 1) * 4096;
    const int sb = 32768 + 4096 - (t & 1) * 4096;
    if (t < 31) {
      GLDS16(X + (size_t)(m0 + rowA) * DM + (t + 1) * 32 + kqA * 8,
             sb + w * 1024, lds);
      WAITV(1);
    } else {
      WAITV(0);
    }
    __builtin_amdgcn_s_barrier();
    __builtin_amdgcn_sched_barrier(0);
    short8 af  = *(const short8*)(lds + cb + offA);
    short8 bfv = *(const short8*)(lds + t * 1024 + offB);
    acc = __builtin_amdgcn_mfma_f32_16x16x32_bf16(af, bfv, acc, 0, 0, 0);
    __builtin_amdgcn_s_barrier();
  }
  float bb = Bb[fm];
#pragma unroll
  for (int q = 0; q < 4; ++q) {
    int row = m0 + w * 16 + fq * 4 + q;
    Bx[(size_t)row * DSTATE + fm] = acc[q] + bb;
  }
}

// ---------------------------------------------------------------------------
// K3: chunked scan (round-5 proven, __expf tanh).
// ---------------------------------------------------------------------------
__global__ __launch_bounds__(64) void scan_kernel(const float* __restrict__ A,
                                                  const float* __restrict__ Bx,
                                                  float* __restrict__ st) {
  int lane = threadIdx.x;
  int n    = lane & 15;
  int base = lane & 48;
  int chain = blockIdx.x * 4 + (lane >> 4);
  int c = chain >> 3;
  int b = chain & 7;

  float Arow[16];
#pragma unroll
  for (int m = 0; m < 16; m++) Arow[m] = A[n * 16 + m];

  int t0   = (c == 0) ? 0 : c * CHUNK - WARM;
  int t1   = c * CHUNK;
  int tEnd = c * CHUNK + CHUNK;

  const float* bxp = Bx + (size_t)b * SEQ * DSTATE + n;
  float*       stp = st + (size_t)b * SEQ * DSTATE + n;

  float state = 0.f;
  for (int t = t0; t < tEnd; t++) {
    float a = bxp[(size_t)t * DSTATE];
#pragma unroll
    for (int m = 0; m < 16; m++)
      a += Arow[m] * __shfl(state, base + m, 64);
    float e = __expf(-2.f * fabsf(a));
    float r = (1.f - e) / (1.f + e);
    state = __builtin_copysignf(r, a);
    if (t >= t1) stp[(size_t)t * DSTATE] = state;
  }
}

// ---------------------------------------------------------------------------
// K4: FUSED gate GEMM + SSM output + gating + residual + LN.
// Round-4 proven FBM=32 structure (clean regs, clean stores) with the
// per-step vmcnt(0) drain replaced by counted vmcnt (T4): per step each
// wave issues 8 Gw loads (+1 A/st for waves 0-1); s_waitcnt vmcnt(L)
// leaves the just-issued tile in flight while guaranteeing tile t landed.
// Raw s_barrier (no drain); buffer-reuse safety: all ds_reads of a tile
// are consumed by MFMAs before the tail barrier (lgkmcnt-ordered).
// ---------------------------------------------------------------------------
#define FBM 32
#define FBK 32
#define NT  (DM / FBK)          // 32
#define BUFB 67584              // A [0,2048) + B [2048,67584)
#define CW_OFF 0                // epilogue Cw (64KB, overlays buf0)
#define ST_OFF 65536            // epilogue st (2KB, tail of buf0)
#define PART_OFF 67584          // LN partials: 8 waves x 32 rows x 8B = 2KB
#define TOT_OFF 69632           // LN (mu, inv) per row: 32 x 8B
#define BOUNCE 71680            // 16 rows x 4KB = 64KB store-bounce
// total LDS: 71680 + 65536 = 137216 <= 160K -> 1 block/CU

__global__ __launch_bounds__(512, 2) void fused_kernel(
    const bf16* __restrict__ X, const bf16* __restrict__ Gw,
    const float* __restrict__ xf, const float* __restrict__ st,
    const float* __restrict__ Cw, const float* __restrict__ Cb,
    const float* __restrict__ Dv, const float* __restrict__ gb,
    const float* __restrict__ lng, const float* __restrict__ lnb,
    float* __restrict__ out) {
  __shared__ __align__(16) char lds[137216];
  const int tid  = threadIdx.x;
  const int lane = tid & 63;
  const int w    = tid >> 6;        // wave 0..7
  const int fm   = lane & 15;
  const int fq   = lane >> 4;
  const int m0   = blockIdx.x * FBM;
  const int l4   = lane >> 2, lk = lane & 3;

  // staging source constants (pre-swizzled global addresses)
  int colS[8], kqS[8];
#pragma unroll
  for (int s = 0; s < 8; s++) {
    int col = (w * 8 + s) * 16 + l4;
    colS[s] = col;
    kqS[s]  = lk ^ ((col >> 1) & 3);
  }
  const int rowA = w * 16 + l4;     // valid for w<2
  const int kqA  = lk ^ ((rowA >> 1) & 3);

  // fragment read byte offsets (swizzled)
  int offA[2], offB[8];
#pragma unroll
  for (int i = 0; i < 2; i++) {
    int r = i * 16 + fm;
    offA[i] = r * 64 + ((fq ^ ((r >> 1) & 3)) << 4);
  }
#pragma unroll
  for (int j = 0; j < 8; j++) {
    int c = w * 128 + j * 16 + fm;
    offB[j] = 2048 + c * 64 + ((fq ^ ((c >> 1) & 3)) << 4);
  }

  f32x4 acc[2][8];
#pragma unroll
  for (int i = 0; i < 2; i++)
#pragma unroll
    for (int j = 0; j < 8; j++) acc[i][j] = (f32x4)(0.f);

  // prologue: tile 0 -> buf0 (no barrier; loop's wait+barrier covers it)
  {
#pragma unroll
    for (int s = 0; s < 8; s++)
      GLDS16(Gw + (size_t)colS[s] * DM + kqS[s] * 8,
             2048 + (w * 8 + s) * 1024, lds);
    if (w < 2)
      GLDS16(X + (size_t)(m0 + rowA) * DM + kqA * 8, w * 1024, lds);
  }

  for (int t = 0; t < NT; t++) {
    const int cb = (t & 1) * BUFB;  // compute buffer base
    const int sb = BUFB - cb;       // stage buffer base
    if (t < NT - 1) {
      const int kb = (t + 1) * FBK;
#pragma unroll
      for (int s = 0; s < 8; s++)
        GLDS16(Gw + (size_t)colS[s] * DM + kb + kqS[s] * 8,
               sb + 2048 + (w * 8 + s) * 1024, lds);
      if (w < 2)
        GLDS16(X + (size_t)(m0 + rowA) * DM + kb + kqA * 8, sb + w * 1024, lds);
    } else {
      // last K-step (computes from buf1): stage epilogue into buf0
#pragma unroll
      for (int s = 0; s < 8; s++) {
        int c   = w * 8 + s;
        int col = c * 16 + l4;
        int nq  = lk ^ ((col >> 1) & 3);
        GLDS16(Cw + (size_t)col * DSTATE + nq * 4, CW_OFF + c * 1024, lds);
      }
      if (w < 2) {
        int cc  = w;
        int row = cc * 16 + l4;
        int nq  = lk ^ ((row >> 1) & 3);
        GLDS16(st + (size_t)(m0 + row) * DSTATE + nq * 4, ST_OFF + cc * 1024, lds);
      }
    }

    // counted wait: leave just-issued tile in flight, ensure tile t landed
    if (w < 2) WAITV(9); else WAITV(8);
    __builtin_amdgcn_s_barrier();
    __builtin_amdgcn_sched_barrier(0);

    short8 af[2];
#pragma unroll
    for (int i = 0; i < 2; i++) af[i] = *(const short8*)(lds + cb + offA[i]);
#pragma unroll
    for (int j = 0; j < 8; j++) {
      short8 bfj = *(const short8*)(lds + cb + offB[j]);
#pragma unroll
      for (int i = 0; i < 2; i++)
        acc[i][j] = __builtin_amdgcn_mfma_f32_16x16x32_bf16(af[i], bfj,
                                                            acc[i][j], 0, 0, 0);
    }
    __builtin_amdgcn_s_barrier();
  }
  __syncthreads();   // drains epilogue staging (vmcnt 0) + barrier

  // ---- epilogue phase 1: z2 = g*oc + (1-g)*x + x, row partial sums
#pragma unroll
  for (int i = 0; i < 2; i++) {
    f32x4 stv[4][4];   // [nq][r]
#pragma unroll
    for (int nq = 0; nq < 4; nq++)
#pragma unroll
      for (int r = 0; r < 4; r++) {
        int row = i * 16 + fq * 4 + r;
        stv[nq][r] = *(const f32x4*)(lds + ST_OFF + row * 64 +
                                     ((nq ^ ((row >> 1) & 3)) << 4));
      }
    float sum4[4] = {0.f, 0.f, 0.f, 0.f};
    float ssq4[4] = {0.f, 0.f, 0.f, 0.f};
#pragma unroll
    for (int j = 0; j < 8; j++) {
      int c = w * 128 + j * 16 + fm;
      float oc[4] = {0.f, 0.f, 0.f, 0.f};
#pragma unroll
      for (int nq = 0; nq < 4; nq++) {
        f32x4 cw = *(const f32x4*)(lds + CW_OFF + c * 64 +
                                   ((nq ^ ((c >> 1) & 3)) << 4));
#pragma unroll
        for (int r = 0; r < 4; r++)
          oc[r] += stv[nq][r][0] * cw[0] + stv[nq][r][1] * cw[1] +
                   stv[nq][r][2] * cw[2] + stv[nq][r][3] * cw[3];
      }
      float gbv = gb[c], cbv = Cb[c], dvv = Dv[c];
#pragma unroll
      for (int r = 0; r < 4; r++) {
        int   grow = m0 + i * 16 + fq * 4 + r;
        float xv = xf[(size_t)grow * DM + c];
        float zg = acc[i][j][r] + gbv;
        float g  = zg / (1.f + __expf(-zg));
        float ocf = oc[r] + cbv + dvv * xv;
        float y  = g * ocf + (1.f - g) * xv;
        float z2 = y + xv;
        acc[i][j][r] = z2;
        sum4[r] += z2;
        ssq4[r] += z2 * z2;
      }
    }
#pragma unroll
    for (int r = 0; r < 4; r++) {
#pragma unroll
      for (int off = 1; off < 16; off <<= 1) {
        sum4[r] += __shfl_xor(sum4[r], off, 64);
        ssq4[r] += __shfl_xor(ssq4[r], off, 64);
      }
    }
    if (fm == 0) {
#pragma unroll
      for (int r = 0; r < 4; r++) {
        int row = i * 16 + fq * 4 + r;
        *(float2*)(lds + PART_OFF + w * 256 + row * 8) =
            make_float2(sum4[r], ssq4[r]);
      }
    }
  }
  __syncthreads();

  if (tid < 32) {
    float s = 0.f, q = 0.f;
#pragma unroll
    for (int ww = 0; ww < 8; ww++) {
      float2 p = *(const float2*)(lds + PART_OFF + ww * 256 + tid * 8);
      s += p.x; q += p.y;
    }
    float mu  = s * (1.f / DM);
    float var = q * (1.f / DM) - mu * mu;
    *(float2*)(lds + TOT_OFF + tid * 8) = make_float2(mu, rsqrtf(var + LNEPS));
  }
  __syncthreads();

  // ---- epilogue phase 2: bounce raw z2 through LDS, store float4 full lines
  for (int h = 0; h < 2; ++h) {
#pragma unroll
    for (int j = 0; j < 8; ++j) {
      int c = w * 128 + j * 16 + fm;
#pragma unroll
      for (int r = 0; r < 4; ++r) {
        int row16 = fq * 4 + r;
        *(float*)(lds + BOUNCE + row16 * 4096 + c * 4) = acc[h][j][r];
      }
    }
    __syncthreads();
    {
      int row16 = tid >> 5;
      int lbase = (tid & 31) * 4;
      float2 mi = *(const float2*)(lds + TOT_OFF + (h * 16 + row16) * 8);
#pragma unroll
      for (int q = 0; q < 8; ++q) {
        int col = lbase + q * 128;
        f32x4 z = *(const f32x4*)(lds + BOUNCE + row16 * 4096 + col * 4);
        float4 g4 = *(const float4*)(lng + col);
        float4 b4 = *(const float4*)(lnb + col);
        float4 ov;
        ov.x = (z[0] - mi.x) * mi.y * g4.x + b4.x;
        ov.y = (z[1] - mi.x) * mi.y * g4.y + b4.y;
        ov.z = (z[2] - mi.x) * mi.y * g4.z + b4.z;
        ov.w = (z[3] - mi.x) * mi.y * g4.w + b4.w;
        *(float4*)(out + (size_t)(m0 + h * 16 + row16) * DM + col) = ov;
      }
    }
    __syncthreads();
  }
}

// ---------------------------------------------------------------------------
extern "C" void kernel_launch(void* const* d_in, const int* in_sizes, int n_in,
                              void* d_out, int out_size, void* d_ws, size_t ws_size,
                              hipStream_t stream) {
  (void)in_sizes; (void)n_in;
  const float* x   = (const float*)d_in[0];
  const float* A   = (const float*)d_in[1];
  const float* Bw  = (const float*)d_in[2];
  const float* Bb  = (const float*)d_in[3];
  const float* Cw  = (const float*)d_in[4];
  const float* Cb  = (const float*)d_in[5];
  const float* Dv  = (const float*)d_in[6];
  const float* Gw  = (const float*)d_in[7];
  const float* gb  = (const float*)d_in[8];
  const float* lng = (const float*)d_in[9];
  const float* lnb = (const float*)d_in[10];
  float* out = (float*)d_out;

  const size_t NEED = (size_t)72 << 20;
  if (ws_size < NEED) {
    hipMemsetAsync(d_out, 0, (size_t)out_size * 4, stream);
    return;
  }

  char* ws = (char*)d_ws;
  bf16*  wsx = (bf16*)(ws);                          // 64 MB bf16 x
  bf16*  gwc = (bf16*)(ws + ((size_t)64 << 20));     // 2 MB bf16 gate_w
  float* Bx  = (float*)(ws + ((size_t)66 << 20));    // 2 MB
  float* st  = (float*)(ws + ((size_t)68 << 20));    // 2 MB

  canon_all<<<XBLK + GBLK, 256, 0, stream>>>(x, Gw, wsx, gwc);
  bx_kernel<<<MROWS / 64, 256, 0, stream>>>(wsx, Bw, Bb, Bx);
  scan_kernel<<<(BATCH * NCHUNK) / 4, 64, 0, stream>>>(A, Bx, st);
  fused_kernel<<<MROWS / FBM, 512, 0, stream>>>(
      wsx, gwc, x, st, Cw, Cb, Dv, gb, lng, lnb, out);
}